// Round 9
// baseline (150.124 us; speedup 1.0000x reference)
//
#include <hip/hip_runtime.h>

// Problem constants (from reference)
#define TDIM   1024          // TOKEN_DIM
#define HID    256           // HIDDEN
#define FDIM   63            // 3*(2*10+1)
#define INDIM  1087          // TDIM + FDIM
#define TT     512           // T
#define NBATCH 2             // B
#define ROWS   4             // rows per block in decode_tail kernel
#define KC     64            // k-chunk for stage1 LDS staging
#define EPS_LN   1e-5f
#define EPS_NORM 1e-12f

__device__ __forceinline__ float wave_reduce_sum(float v) {
    #pragma unroll
    for (int m = 32; m >= 1; m >>= 1) v += __shfl_xor(v, m);
    return v;
}

// ============================================================================
// K1: stage-1 GEMM  h1_pre[1024][256] = combined[1024][1087] @ W1 + b1
// Grid: 64 rowtiles(16 rows) x 4 colgroups(64 cols) = 256 blocks, 256 threads.
// Per thread: 4 output rows x 1 col. Rows are wave-uniform -> LDS broadcasts.
// W1 re-read only 64x (per rowtile) instead of 256x -> L2 time ~1us < VALU.
// ============================================================================
__global__ __launch_bounds__(256) void stage1_kernel(
    const float* __restrict__ tokens,   // (1024,1024) flat
    const float* __restrict__ anchors,  // (1024,3) flat
    const float* __restrict__ W1,       // (1087,256) row-major
    const float* __restrict__ b1,       // (256)
    float* __restrict__ h1_pre)         // (1024,256)
{
    __shared__ float comb_lds[16][KC];  // token k-chunk for the 16 rows
    __shared__ float fr_lds[16][64];    // fourier features (63 used) per row

    const int tid     = threadIdx.x;
    const int rt      = blockIdx.x >> 2;          // 0..63 row tile
    const int cg      = blockIdx.x & 3;           // 0..3 col group
    const int rowbase = rt * 16;
    const int col     = (cg << 6) + (tid & 63);   // output column 0..255
    const int rg4     = (tid >> 6) << 2;          // first of this thread's 4 rows (0,4,8,12)

    // ---- Fourier features for the 16 rows (16*63 = 1008 values) ----
    for (int u0 = tid; u0 < 16 * FDIM; u0 += 256) {
        const int r = u0 / FDIM;
        const int u = u0 % FDIM;
        const int c = u / 21;     // coord 0..2
        const int w = u % 21;     // 0 = identity, 1..10 = sin, 11..20 = cos
        const float x = anchors[(size_t)(rowbase + r) * 3 + c];
        float v;
        if (w == 0)       v = x;
        else if (w <= 10) v = sinf(x * (float)(1u << (w - 1)));
        else              v = cosf(x * (float)(1u << (w - 11)));
        fr_lds[r][u] = v;
    }

    float acc0 = b1[col];
    float acc1 = acc0, acc2 = acc0, acc3 = acc0;

    // staging map: each thread stages one float4; 16 rows x 64 floats per chunk
    const int sr = tid >> 4;          // 0..15 stage row
    const int sj = (tid & 15) << 2;   // 0,4,...,60

    // prefetch chunk 0 (registers)
    float4 pf = *(const float4*)&tokens[(size_t)(rowbase + sr) * TDIM + sj];
    __syncthreads();   // fr_lds visible before anyone might read it later

    // ---- main loop: 16 chunks of 64 k-values (covers k = 0..1023) ----
    for (int c = 0; c < 16; ++c) {
        *(float4*)&comb_lds[sr][sj] = pf;
        __syncthreads();
        if (c < 15)
            pf = *(const float4*)&tokens[(size_t)(rowbase + sr) * TDIM + (c + 1) * KC + sj];
        const int k0 = c * KC;
        const float* __restrict__ wp = W1 + (size_t)k0 * HID + col;
        #pragma unroll
        for (int kk = 0; kk < KC; kk += 4) {
            const float w0 = wp[(size_t)(kk    ) * HID];
            const float w1 = wp[(size_t)(kk + 1) * HID];
            const float w2 = wp[(size_t)(kk + 2) * HID];
            const float w3 = wp[(size_t)(kk + 3) * HID];
            const float4 c0 = *(const float4*)&comb_lds[rg4 + 0][kk];
            const float4 c1 = *(const float4*)&comb_lds[rg4 + 1][kk];
            const float4 c2 = *(const float4*)&comb_lds[rg4 + 2][kk];
            const float4 c3 = *(const float4*)&comb_lds[rg4 + 3][kk];
            acc0 = fmaf(c0.x, w0, acc0); acc0 = fmaf(c0.y, w1, acc0);
            acc0 = fmaf(c0.z, w2, acc0); acc0 = fmaf(c0.w, w3, acc0);
            acc1 = fmaf(c1.x, w0, acc1); acc1 = fmaf(c1.y, w1, acc1);
            acc1 = fmaf(c1.z, w2, acc1); acc1 = fmaf(c1.w, w3, acc1);
            acc2 = fmaf(c2.x, w0, acc2); acc2 = fmaf(c2.y, w1, acc2);
            acc2 = fmaf(c2.z, w2, acc2); acc2 = fmaf(c2.w, w3, acc2);
            acc3 = fmaf(c3.x, w0, acc3); acc3 = fmaf(c3.y, w1, acc3);
            acc3 = fmaf(c3.z, w2, acc3); acc3 = fmaf(c3.w, w3, acc3);
        }
        __syncthreads();
    }

    // ---- fourier tail: k = 1024..1086 from fr_lds (wave-uniform broadcasts) ----
    const float* __restrict__ wt = W1 + (size_t)TDIM * HID + col;
    for (int kk = 0; kk < FDIM; ++kk) {
        const float w = wt[(size_t)kk * HID];
        acc0 = fmaf(fr_lds[rg4 + 0][kk], w, acc0);
        acc1 = fmaf(fr_lds[rg4 + 1][kk], w, acc1);
        acc2 = fmaf(fr_lds[rg4 + 2][kk], w, acc2);
        acc3 = fmaf(fr_lds[rg4 + 3][kk], w, acc3);
    }

    // ---- store 4 rows x 1 col ----
    h1_pre[(size_t)(rowbase + rg4 + 0) * HID + col] = acc0;
    h1_pre[(size_t)(rowbase + rg4 + 1) * HID + col] = acc1;
    h1_pre[(size_t)(rowbase + rg4 + 2) * HID + col] = acc2;
    h1_pre[(size_t)(rowbase + rg4 + 3) * HID + col] = acc3;
}

// ============================================================================
// K2: LN1+ReLU -> stage2 GEMM -> LN2+ReLU -> stage3 -> postprocess
// Grid: 1024/ROWS = 256 blocks, 256 threads. (audited round-2/3 code)
// ============================================================================
__global__ __launch_bounds__(256) void decode_tail_kernel(
    const float* __restrict__ h1_pre,   // (1024,256)
    const float* __restrict__ g1,
    const float* __restrict__ be1,
    const float* __restrict__ W2,       // (256,256)
    const float* __restrict__ b2,
    const float* __restrict__ g2,
    const float* __restrict__ be2,
    const float* __restrict__ W3,       // (256,14)
    const float* __restrict__ b3,       // (14)
    float* __restrict__ decoded)        // (1024,14)
{
    __shared__ float h1[ROWS][HID];
    __shared__ float h2[ROWS][HID];
    __shared__ float raws[ROWS][16];

    const int tid  = threadIdx.x;
    const int base = blockIdx.x * ROWS;
    const int wave = tid >> 6;
    const int lane = tid & 63;

    // ---- LN1 + ReLU directly from global h1_pre (each wave owns 1 row) ----
    {
        const int r = wave;
        const float* __restrict__ src = h1_pre + (size_t)(base + r) * HID;
        float x0 = src[lane], x1 = src[lane + 64], x2 = src[lane + 128], x3 = src[lane + 192];
        const float ga0 = g1[lane], ga1 = g1[lane + 64], ga2 = g1[lane + 128], ga3 = g1[lane + 192];
        const float bb0 = be1[lane], bb1 = be1[lane + 64], bb2 = be1[lane + 128], bb3 = be1[lane + 192];
        const float s  = wave_reduce_sum(x0 + x1 + x2 + x3);
        const float mu = s * (1.0f / 256.0f);
        const float d0 = x0 - mu, d1 = x1 - mu, d2 = x2 - mu, d3 = x3 - mu;
        const float sq = wave_reduce_sum(d0 * d0 + d1 * d1 + d2 * d2 + d3 * d3);
        const float rstd = 1.0f / sqrtf(sq * (1.0f / 256.0f) + EPS_LN);
        h1[r][lane]       = fmaxf(0.0f, fmaf(d0 * rstd, ga0, bb0));
        h1[r][lane + 64]  = fmaxf(0.0f, fmaf(d1 * rstd, ga1, bb1));
        h1[r][lane + 128] = fmaxf(0.0f, fmaf(d2 * rstd, ga2, bb2));
        h1[r][lane + 192] = fmaxf(0.0f, fmaf(d3 * rstd, ga3, bb3));
    }
    __syncthreads();

    // ---- Stage 2: h1(256) @ W2 -> 256 ----
    {
        float acc[ROWS];
        const float bias = b2[tid];
        #pragma unroll
        for (int r = 0; r < ROWS; ++r) acc[r] = bias;
        const float* __restrict__ wp = W2 + tid;
        #pragma unroll 8
        for (int k = 0; k < HID; ++k) {
            const float w = wp[(size_t)k * HID];
            #pragma unroll
            for (int r = 0; r < ROWS; ++r) acc[r] = fmaf(h1[r][k], w, acc[r]);
        }
        #pragma unroll
        for (int r = 0; r < ROWS; ++r) h2[r][tid] = acc[r];
    }
    __syncthreads();

    // ---- LN2 + ReLU ----
    {
        const float ga0 = g2[lane], ga1 = g2[lane + 64], ga2 = g2[lane + 128], ga3 = g2[lane + 192];
        const float bb0 = be2[lane], bb1 = be2[lane + 64], bb2 = be2[lane + 128], bb3 = be2[lane + 192];
        const int r = wave;
        float x0 = h2[r][lane], x1 = h2[r][lane + 64], x2 = h2[r][lane + 128], x3 = h2[r][lane + 192];
        const float s  = wave_reduce_sum(x0 + x1 + x2 + x3);
        const float mu = s * (1.0f / 256.0f);
        const float d0 = x0 - mu, d1 = x1 - mu, d2 = x2 - mu, d3 = x3 - mu;
        const float sq = wave_reduce_sum(d0 * d0 + d1 * d1 + d2 * d2 + d3 * d3);
        const float rstd = 1.0f / sqrtf(sq * (1.0f / 256.0f) + EPS_LN);
        h2[r][lane]       = fmaxf(0.0f, fmaf(d0 * rstd, ga0, bb0));
        h2[r][lane + 64]  = fmaxf(0.0f, fmaf(d1 * rstd, ga1, bb1));
        h2[r][lane + 128] = fmaxf(0.0f, fmaf(d2 * rstd, ga2, bb2));
        h2[r][lane + 192] = fmaxf(0.0f, fmaf(d3 * rstd, ga3, bb3));
    }
    __syncthreads();

    // ---- Stage 3: h2(256) @ W3 -> 14 ----
    if (tid < ROWS * 14) {
        const int r = tid / 14;
        const int m = tid % 14;
        float a = b3[m];
        #pragma unroll 4
        for (int k = 0; k < HID; ++k) a = fmaf(h2[r][k], W3[k * 14 + m], a);
        raws[r][m] = a;
    }
    __syncthreads();

    // ---- Postprocess + store ----
    if (tid < ROWS * 14) {
        const int r = tid / 14;
        const int m = tid % 14;
        const float x = raws[r][m];
        float v;
        if (m < 3) {
            v = x;
        } else if (m < 6) {
            v = fminf(fmaxf(x, 0.0f), 1.0f);
        } else if (m == 6) {
            v = 1.0f / (1.0f + expf(-x));
        } else if (m < 10) {
            v = expf(x);
        } else {
            const float q0 = raws[r][10], q1 = raws[r][11];
            const float q2 = raws[r][12], q3 = raws[r][13];
            const float nrm = sqrtf(q0 * q0 + q1 * q1 + q2 * q2 + q3 * q3);
            v = x / fmaxf(nrm, EPS_NORM);
        }
        decoded[(size_t)(base + r) * 14 + m] = v;
    }
}

// One thread per OUTPUT FLOAT -> perfectly coalesced stores.
__global__ __launch_bounds__(256) void gather_kernel(
    const int* __restrict__ ids,        // (2, N) flat
    const float* __restrict__ decoded,  // (1024, 14)
    float* __restrict__ out,            // (2, N*14) flat
    int N, int total14)
{
    const int j = blockIdx.x * blockDim.x + threadIdx.x;
    if (j >= total14) return;
    const int i = j / 14;               // flat (b,n) point index
    const int k = j - i * 14;           // component 0..13
    const int b = (i >= N) ? 1 : 0;
    const int t = ids[i];               // L1-cached: 14 consecutive lanes share i
    out[j] = decoded[(size_t)(b * TT + t) * 14 + k];
}

extern "C" void kernel_launch(void* const* d_in, const int* in_sizes, int n_in,
                              void* d_out, int out_size, void* d_ws, size_t ws_size,
                              hipStream_t stream) {
    const float* tokens  = (const float*)d_in[0];
    const float* anchors = (const float*)d_in[1];
    const int*   ids     = (const int*)d_in[2];
    const float* W1  = (const float*)d_in[3];
    const float* b1  = (const float*)d_in[4];
    const float* g1  = (const float*)d_in[5];
    const float* be1 = (const float*)d_in[6];
    const float* W2  = (const float*)d_in[7];
    const float* b2  = (const float*)d_in[8];
    const float* g2  = (const float*)d_in[9];
    const float* be2 = (const float*)d_in[10];
    const float* W3  = (const float*)d_in[11];
    const float* b3  = (const float*)d_in[12];

    const size_t n_h1   = (size_t)1024 * HID;     // 262144 floats = 1 MB
    const size_t n_dec  = (size_t)1024 * 14;      // 14336 floats = 57 KB

    // decoded always lives in d_ws (57 KB). h1_pre (1 MB) prefers d_ws;
    // falls back to d_out (gather fully rewrites d_out afterwards, stream-ordered).
    float* decoded = (float*)d_ws;
    float* h1_pre;
    if (ws_size >= (n_h1 + n_dec) * sizeof(float)) {
        h1_pre = (float*)d_ws + n_dec;
    } else {
        h1_pre = (float*)d_out;                   // out_size = 1,120,000 floats >= 1 MB
    }
    float* out = (float*)d_out;

    const int N = in_sizes[2] / NBATCH;           // 40000

    stage1_kernel<<<256, 256, 0, stream>>>(tokens, anchors, W1, b1, h1_pre);

    decode_tail_kernel<<<1024 / ROWS, 256, 0, stream>>>(
        h1_pre, g1, be1, W2, b2, g2, be2, W3, b3, decoded);

    const int total14 = NBATCH * N * 14;
    gather_kernel<<<(total14 + 255) / 256, 256, 0, stream>>>(ids, decoded, out, N, total14);
}